// Round 1
// baseline (1323.158 us; speedup 1.0000x reference)
//
#include <hip/hip_runtime.h>
#include <math.h>

// Problem constants
#define NL 2
#define NDIR 4
#define DD 256     // D (channels)
#define DIN 512    // DI (inner)
#define NS 16      // N (state)
#define BB 8       // batch
#define LL 256     // L = H*W
#define BL 2048    // B*L

__device__ __forceinline__ float siluf(float x){ return x / (1.f + expf(-x)); }
__device__ __forceinline__ float sigmoidf(float x){ return 1.f / (1.f + expf(-x)); }
__device__ __forceinline__ float softplusf(float x){ return fmaxf(x, 0.f) + log1pf(expf(-fabsf(x))); }
__device__ __forceinline__ float geluf(float x){ return 0.5f * x * (1.f + erff(x * 0.70710678118654752f)); }
__device__ __forceinline__ int perml(int l, int d){
  int h = l >> 4, w = l & 15;
  if (d & 1) w = 15 - w;
  if (d & 2) h = 15 - h;
  return (h << 4) | w;
}

// feat (B,C,H,W) -> x (B,L,C)
__global__ __launch_bounds__(256) void k_transpose(const float* __restrict__ feat, float* __restrict__ x){
  int idx = blockIdx.x * 256 + threadIdx.x;           // B*L*C = 524288
  int c = idx & 255, l = (idx >> 8) & 255, b = idx >> 16;
  x[idx] = feat[((b * DD + c) * 16 + (l >> 4)) * 16 + (l & 15)];
}

// gate[li,b,c] = sigmoid(alt_embed[alt_idx[b]] . gate_w[li,c,:] + gate_b[li,c])
__global__ __launch_bounds__(256) void k_gate(const float* __restrict__ alt_embed, const int* __restrict__ alt_idx,
                      const float* __restrict__ gate_w, const float* __restrict__ gate_b,
                      float* __restrict__ gate){
  int idx = blockIdx.x * 256 + threadIdx.x;           // NL*B*D = 4096
  int c = idx & 255, b = (idx >> 8) & 7, li = idx >> 11;
  const float* ae = alt_embed + alt_idx[b] * 32;
  const float* gw = gate_w + ((long)li * DD + c) * 32;
  float acc = gate_b[li * DD + c];
  #pragma unroll
  for (int j = 0; j < 32; j++) acc += ae[j] * gw[j];
  gate[idx] = sigmoidf(acc);
}

// seq[d,b,l,c] = x[b, perm_d(l), c]
__global__ __launch_bounds__(256) void k_seq(const float* __restrict__ x, float* __restrict__ seq){
  int idx = blockIdx.x * 256 + threadIdx.x;           // 4*B*L*C
  int c = idx & 255, l = (idx >> 8) & 255, b = (idx >> 16) & 7, d = idx >> 19;
  seq[idx] = x[((b * LL) + perml(l, d)) * DD + c];
}

// Generic tiled fp32 GEMM: C[m,n] = act(sum_k A(m,k)*W[n,k] + bias[n])
// ALAYOUT 0: A row-major (M,K). ALAYOUT 2: A channel-major per-b: addr=(m>>8)*(K*256)+k*256+(m&255)
template<int ALAYOUT, int ACT, bool BIAS>
__global__ __launch_bounds__(256) void k_gemm(const float* __restrict__ A, const float* __restrict__ W,
        const float* __restrict__ bias, float* __restrict__ C,
        int M, int N, int K, long aBatch, long wBatch, long cBatch){
  __shared__ float As[16][65];
  __shared__ float Ws[64][17];
  int m0 = blockIdx.x * 64, n0 = blockIdx.y * 64, d = blockIdx.z;
  int t = threadIdx.x;
  int tx = t & 15, ty = t >> 4;
  const float* Ad = A + (long)d * aBatch;
  const float* Wd = W + (long)d * wBatch;
  float acc[4][4] = {};
  for (int kb = 0; kb < K; kb += 16){
    if (ALAYOUT == 0){
      #pragma unroll
      for (int r = 0; r < 4; r++){
        int e = r * 256 + t; int ml = e >> 4, kl = e & 15;
        As[kl][ml] = Ad[(long)(m0 + ml) * K + kb + kl];
      }
    } else {
      #pragma unroll
      for (int r = 0; r < 4; r++){
        int e = r * 256 + t; int kl = e >> 6, ml = e & 63;
        int m = m0 + ml;
        As[kl][ml] = Ad[(long)(m >> 8) * ((long)K * 256) + (long)(kb + kl) * 256 + (m & 255)];
      }
    }
    #pragma unroll
    for (int r = 0; r < 4; r++){
      int e = r * 256 + t; int nl = e >> 4, kl = e & 15;
      int n = n0 + nl;
      Ws[nl][kl] = (n < N) ? Wd[(long)n * K + kb + kl] : 0.f;
    }
    __syncthreads();
    #pragma unroll
    for (int kk = 0; kk < 16; kk++){
      float a[4], w[4];
      #pragma unroll
      for (int j = 0; j < 4; j++) a[j] = As[kk][ty * 4 + j];
      #pragma unroll
      for (int j = 0; j < 4; j++) w[j] = Ws[tx * 4 + j][kk];
      #pragma unroll
      for (int j = 0; j < 4; j++)
        #pragma unroll
        for (int jj = 0; jj < 4; jj++)
          acc[j][jj] += a[j] * w[jj];
    }
    __syncthreads();
  }
  #pragma unroll
  for (int j = 0; j < 4; j++){
    int m = m0 + ty * 4 + j;
    #pragma unroll
    for (int jj = 0; jj < 4; jj++){
      int n = n0 + tx * 4 + jj;
      if (n < N){
        float v = acc[j][jj];
        if (BIAS) v += bias[n];
        if (ACT == 1) v = geluf(v);
        C[(long)d * cBatch + (long)m * N + n] = v;
      }
    }
  }
}

// causal depthwise conv (K=4) + silu; writes channel-major xct[d,b,i,l]
__global__ __launch_bounds__(256) void k_conv(const float* __restrict__ xz, const float* __restrict__ cw,
                      const float* __restrict__ cb, float* __restrict__ xct){
  int it = blockIdx.x * 64, lc = blockIdx.y * 128, db = blockIdx.z;
  int d = db >> 3;
  int t = threadIdx.x;
  __shared__ float xs[64][131];
  const float* src = xz + (long)db * LL * 1024;
  for (int e = t; e < 131 * 64; e += 256){
    int il = e & 63, lh = e >> 6;
    int gl = lc - 3 + lh;
    xs[il][lh] = (gl >= 0) ? src[(long)gl * 1024 + it + il] : 0.f;
  }
  __syncthreads();
  const float* cwp = cw + ((long)d * DIN + it) * 4;
  const float* cbp = cb + (long)d * DIN + it;
  for (int e = t; e < 64 * 128; e += 256){
    int ll = e & 127, il = e >> 7;
    float acc = cbp[il];
    #pragma unroll
    for (int k = 0; k < 4; k++) acc += xs[il][ll + k] * cwp[il * 4 + k];
    xct[((long)db * DIN + it + il) * LL + lc + ll] = siluf(acc);
  }
}

// silu(z) transposed to channel-major zst[d,b,i,l]
__global__ __launch_bounds__(256) void k_zsilu(const float* __restrict__ xz, float* __restrict__ zst){
  int it = blockIdx.x * 64, lc = blockIdx.y * 128, db = blockIdx.z;
  int t = threadIdx.x;
  __shared__ float xs[64][129];
  const float* src = xz + (long)db * LL * 1024 + DIN;
  for (int e = t; e < 128 * 64; e += 256){
    int il = e & 63, lh = e >> 6;
    xs[il][lh] = src[(long)(lc + lh) * 1024 + it + il];
  }
  __syncthreads();
  for (int e = t; e < 64 * 128; e += 256){
    int ll = e & 127, il = e >> 7;
    zst[((long)db * DIN + it + il) * LL + lc + ll] = siluf(xs[il][ll]);
  }
}

// dt[d,b,i,l] = softplus(x_dbl[d,b,l,0:16] . dt_w[i,:] + dt_b[i]), channel-major out
__global__ __launch_bounds__(256) void k_dt(const float* __restrict__ x_dbl, const float* __restrict__ dt_w,
                     const float* __restrict__ dt_b, float* __restrict__ dtt){
  int it = blockIdx.x * 64, db = blockIdx.y;
  int d = db >> 3;
  int t = threadIdx.x;
  __shared__ float xs[256][17];
  __shared__ float wt[64][16];
  const float* xd = x_dbl + (long)db * LL * 48;
  for (int e = t; e < 256 * 16; e += 256){ int l = e >> 4, s = e & 15; xs[l][s] = xd[l * 48 + s]; }
  const float* wp = dt_w + ((long)d * DIN + it) * 16;
  for (int e = t; e < 64 * 16; e += 256){ wt[e >> 4][e & 15] = wp[e]; }
  __syncthreads();
  const float* bp = dt_b + (long)d * DIN + it;
  for (int r = 0; r < 64; r++){
    float acc = bp[r];
    #pragma unroll
    for (int s = 0; s < 16; s++) acc += xs[t][s] * wt[r][s];
    dtt[((long)db * DIN + it + r) * LL + t] = softplusf(acc);
  }
}

// windowed scan (K=8): y[l,i] = (sum_k dtc[l-k]*xc[l-k]*sum_s prod(E)*Bp[l-k,s]*Cp[l,s] + D_i*xc[l]) * silu(z)
__global__ __launch_bounds__(256) void k_scan(const float* __restrict__ dtt, const float* __restrict__ xct,
        const float* __restrict__ zst, const float* __restrict__ x_dbl,
        const float* __restrict__ A_log, const float* __restrict__ Dp, float* __restrict__ yt){
  int i = blockIdx.x, b = blockIdx.y, d = blockIdx.z;
  int l = threadIdx.x;
  int db = d * BB + b;
  long base = ((long)db * DIN + i) * LL + l;
  __shared__ float E[256][17];
  __shared__ float Bps[256][17];
  __shared__ float dts[256];
  __shared__ float xcs[256];
  float dto = dtt[base];
  float xco = xct[base];
  dts[l] = dto; xcs[l] = xco;
  const float* alp = A_log + ((long)d * DIN + i) * NS;
  const float* xd = x_dbl + ((long)db * LL + l) * 48;
  float Cp[16];
  #pragma unroll
  for (int s = 0; s < 16; s++){
    float Av = -expf(alp[s]);
    E[l][s] = expf(Av * dto);
    Bps[l][s] = xd[16 + s];
    Cp[s] = xd[32 + s];
  }
  __syncthreads();
  float dec[16];
  #pragma unroll
  for (int s = 0; s < 16; s++) dec[s] = 1.f;
  float c0 = 0.f;
  #pragma unroll
  for (int s = 0; s < 16; s++) c0 += Bps[l][s] * Cp[s];
  float acc = dto * xco * c0;
  for (int k = 1; k < 8; k++){
    int j = l - k;
    if (j < 0) break;
    float c = 0.f;
    #pragma unroll
    for (int s = 0; s < 16; s++){ dec[s] *= E[j + 1][s]; c += dec[s] * Bps[j][s] * Cp[s]; }
    acc += dts[j] * xcs[j] * c;
  }
  float y = (acc + Dp[(long)d * DIN + i] * xco) * zst[base];
  yt[base] = y;
}

// LN over C of (out_pre + residual), write unflipped into comb[b, t, d*256+c]
__global__ __launch_bounds__(256) void k_ln1(const float* __restrict__ out_pre, const float* __restrict__ seq,
        const float* __restrict__ ng, const float* __restrict__ nb, float* __restrict__ comb){
  int l = blockIdx.x, b = blockIdx.y, d = blockIdx.z, c = threadIdx.x;
  long row = ((long)(d * BB + b) * LL + l) * DD;
  float v = out_pre[row + c] + seq[row + c];
  float s = v, q = v * v;
  #pragma unroll
  for (int off = 32; off; off >>= 1){ s += __shfl_down(s, off); q += __shfl_down(q, off); }
  __shared__ float ps[4], pq[4], mv[2];
  int wid = c >> 6;
  if ((c & 63) == 0){ ps[wid] = s; pq[wid] = q; }
  __syncthreads();
  if (c == 0){
    float ts = ps[0] + ps[1] + ps[2] + ps[3];
    float tq = pq[0] + pq[1] + pq[2] + pq[3];
    float m = ts / 256.f;
    mv[0] = m; mv[1] = rsqrtf(tq / 256.f - m * m + 1e-5f);
  }
  __syncthreads();
  float o = (v - mv[0]) * mv[1] * ng[d * DD + c] + nb[d * DD + c];
  comb[((long)b * LL + perml(l, d)) * 1024 + d * DD + c] = o;
}

// LN over C + gate multiply; writes x for next layer or final output
__global__ __launch_bounds__(256) void k_ln2(const float* __restrict__ h2, const float* __restrict__ lg,
        const float* __restrict__ lb, const float* __restrict__ gate, float* __restrict__ dst){
  int l = blockIdx.x, b = blockIdx.y, c = threadIdx.x;
  long row = ((long)b * LL + l) * DD;
  float v = h2[row + c];
  float s = v, q = v * v;
  #pragma unroll
  for (int off = 32; off; off >>= 1){ s += __shfl_down(s, off); q += __shfl_down(q, off); }
  __shared__ float ps[4], pq[4], mv[2];
  int wid = c >> 6;
  if ((c & 63) == 0){ ps[wid] = s; pq[wid] = q; }
  __syncthreads();
  if (c == 0){
    float ts = ps[0] + ps[1] + ps[2] + ps[3];
    float tq = pq[0] + pq[1] + pq[2] + pq[3];
    float m = ts / 256.f;
    mv[0] = m; mv[1] = rsqrtf(tq / 256.f - m * m + 1e-5f);
  }
  __syncthreads();
  float o = (v - mv[0]) * mv[1] * lg[c] + lb[c];
  dst[row + c] = o * gate[b * DD + c];
}

extern "C" void kernel_launch(void* const* d_in, const int* in_sizes, int n_in,
                              void* d_out, int out_size, void* d_ws, size_t ws_size,
                              hipStream_t stream){
  const float* feat     = (const float*)d_in[0];
  const int*   alt_idx  = (const int*)d_in[1];
  const float* in_w     = (const float*)d_in[2];
  const float* dt_w     = (const float*)d_in[3];
  const float* dt_b     = (const float*)d_in[4];
  const float* A_log    = (const float*)d_in[5];
  const float* Dp       = (const float*)d_in[6];
  const float* xp_w     = (const float*)d_in[7];
  const float* conv_w   = (const float*)d_in[8];
  const float* conv_b   = (const float*)d_in[9];
  const float* out_w    = (const float*)d_in[10];
  const float* ng       = (const float*)d_in[11];
  const float* nb       = (const float*)d_in[12];
  const float* fw1      = (const float*)d_in[13];
  const float* fb1      = (const float*)d_in[14];
  const float* fw2      = (const float*)d_in[15];
  const float* fb2      = (const float*)d_in[16];
  const float* flg      = (const float*)d_in[17];
  const float* flb      = (const float*)d_in[18];
  const float* alt_embed= (const float*)d_in[19];
  const float* gate_w   = (const float*)d_in[20];
  const float* gate_b   = (const float*)d_in[21];
  float* out = (float*)d_out;

  float* p = (float*)d_ws;
  float* x_buf = p; p += (long)BL * DD;          // 524288
  float* seq   = p; p += 4L * BL * DD;           // 2M
  float* xz    = p; p += 4L * BL * 1024;         // 8.4M
  float* xct   = p; p += 4L * BB * DIN * LL;     // 4.2M
  float* zst   = p; p += 4L * BB * DIN * LL;
  float* xdbl  = p; p += 4L * BL * 48;
  float* dtt   = p; p += 4L * BB * DIN * LL;
  float* ytb   = p; p += 4L * BB * DIN * LL;
  float* opre  = p; p += 4L * BL * DD;
  float* comb  = p; p += (long)BL * 1024;
  float* hfu   = p; p += (long)BL * 512;
  float* h2    = p; p += (long)BL * DD;
  float* gateb = p; p += 2L * BB * DD;

  k_transpose<<<2048, 256, 0, stream>>>(feat, x_buf);
  k_gate<<<16, 256, 0, stream>>>(alt_embed, alt_idx, gate_w, gate_b, gateb);

  for (int li = 0; li < NL; li++){
    k_seq<<<8192, 256, 0, stream>>>(x_buf, seq);
    // xz = seq @ in_w^T  (batched over 4 dirs)
    k_gemm<0, 0, false><<<dim3(32, 16, 4), 256, 0, stream>>>(
        seq, in_w + (long)li * NDIR * 1024 * 256, nullptr, xz,
        BL, 1024, 256, (long)BL * 256, 1024L * 256, (long)BL * 1024);
    k_conv<<<dim3(8, 2, 32), 256, 0, stream>>>(xz, conv_w + (long)li * NDIR * DIN * 4,
                                               conv_b + (long)li * NDIR * DIN, xct);
    k_zsilu<<<dim3(8, 2, 32), 256, 0, stream>>>(xz, zst);
    // x_dbl = x_conv @ xp_w^T  (N=48)
    k_gemm<2, 0, false><<<dim3(32, 1, 4), 256, 0, stream>>>(
        xct, xp_w + (long)li * NDIR * 48 * 512, nullptr, xdbl,
        BL, 48, 512, (long)BB * DIN * LL, 48L * 512, (long)BL * 48);
    k_dt<<<dim3(8, 32), 256, 0, stream>>>(xdbl, dt_w + (long)li * NDIR * DIN * 16,
                                          dt_b + (long)li * NDIR * DIN, dtt);
    k_scan<<<dim3(512, 8, 4), 256, 0, stream>>>(dtt, xct, zst, xdbl,
        A_log + (long)li * NDIR * DIN * NS, Dp + (long)li * NDIR * DIN, ytb);
    // out_pre = y @ out_w^T
    k_gemm<2, 0, false><<<dim3(32, 4, 4), 256, 0, stream>>>(
        ytb, out_w + (long)li * NDIR * 256 * 512, nullptr, opre,
        BL, 256, 512, (long)BB * DIN * LL, 256L * 512, (long)BL * 256);
    k_ln1<<<dim3(256, 8, 4), 256, 0, stream>>>(opre, seq, ng + (long)li * NDIR * DD,
                                               nb + (long)li * NDIR * DD, comb);
    // hfu = gelu(comb @ fw1^T + fb1)
    k_gemm<0, 1, true><<<dim3(32, 8, 1), 256, 0, stream>>>(
        comb, fw1 + (long)li * 512 * 1024, fb1 + (long)li * 512, hfu,
        BL, 512, 1024, 0, 0, 0);
    // h2 = comb2 @ fw2^T + fb2
    k_gemm<0, 0, true><<<dim3(32, 4, 1), 256, 0, stream>>>(
        hfu, fw2 + (long)li * 256 * 512, fb2 + (long)li * 256, h2,
        BL, 256, 512, 0, 0, 0);
    float* dst = (li == NL - 1) ? out : x_buf;
    k_ln2<<<dim3(256, 8), 256, 0, stream>>>(h2, flg + (long)li * DD, flb + (long)li * DD,
                                            gateb + (long)li * BB * DD, dst);
  }
}

// Round 2
// 888.657 us; speedup vs baseline: 1.4889x; 1.4889x over previous
//
#include <hip/hip_runtime.h>
#include <math.h>

// Problem constants
#define NL 2
#define NDIR 4
#define DD 256     // D (channels)
#define DIN 512    // DI (inner)
#define NS 16      // N (state)
#define BB 8       // batch
#define LL 256     // L = H*W
#define BL 2048    // B*L

typedef short s16x8 __attribute__((ext_vector_type(8)));
typedef short s16x4 __attribute__((ext_vector_type(4)));
typedef float f32x4 __attribute__((ext_vector_type(4)));

__device__ __forceinline__ float siluf(float x){ return x / (1.f + expf(-x)); }
__device__ __forceinline__ float sigmoidf(float x){ return 1.f / (1.f + expf(-x)); }
__device__ __forceinline__ float softplusf(float x){ return fmaxf(x, 0.f) + log1pf(expf(-fabsf(x))); }
__device__ __forceinline__ float geluf(float x){ return 0.5f * x * (1.f + erff(x * 0.70710678118654752f)); }
__device__ __forceinline__ short cvtbf(float f){
  unsigned u = __float_as_uint(f);
  u += 0x7FFF + ((u >> 16) & 1);
  return (short)(u >> 16);
}
__device__ __forceinline__ int perml(int l, int d){
  int h = l >> 4, w = l & 15;
  if (d & 1) w = 15 - w;
  if (d & 2) h = 15 - h;
  return (h << 4) | w;
}

// feat (B,C,H,W) -> x (B,L,C)
__global__ __launch_bounds__(256) void k_transpose(const float* __restrict__ feat, float* __restrict__ x){
  int idx = blockIdx.x * 256 + threadIdx.x;
  int c = idx & 255, l = (idx >> 8) & 255, b = idx >> 16;
  x[idx] = feat[((b * DD + c) * 16 + (l >> 4)) * 16 + (l & 15)];
}

__global__ __launch_bounds__(256) void k_gate(const float* __restrict__ alt_embed, const int* __restrict__ alt_idx,
                      const float* __restrict__ gate_w, const float* __restrict__ gate_b,
                      float* __restrict__ gate){
  int idx = blockIdx.x * 256 + threadIdx.x;
  int c = idx & 255, b = (idx >> 8) & 7, li = idx >> 11;
  const float* ae = alt_embed + alt_idx[b] * 32;
  const float* gw = gate_w + ((long)li * DD + c) * 32;
  float acc = gate_b[li * DD + c];
  #pragma unroll
  for (int j = 0; j < 32; j++) acc += ae[j] * gw[j];
  gate[idx] = sigmoidf(acc);
}

// seq[d,b,l,c] = x[b, perm_d(l), c]  (fp32 + bf16 copies)
__global__ __launch_bounds__(256) void k_seq(const float* __restrict__ x, float* __restrict__ seq,
                                             short* __restrict__ seq_bf){
  int idx = blockIdx.x * 256 + threadIdx.x;
  int c = idx & 255, l = (idx >> 8) & 255, b = (idx >> 16) & 7, d = idx >> 19;
  float v = x[((b * LL) + perml(l, d)) * DD + c];
  seq[idx] = v;
  seq_bf[idx] = cvtbf(v);
}

// MFMA bf16 GEMM: C[m,n] = act(sum_k A[m,k]*W[n,k] + bias[n])
// A: bf16 row-major (M,K). W: fp32 (N,K), converted during staging.
// Block = 4 waves arranged WM x WN, each wave computes 64x64. Tile TM=WM*64, TN=WN*64.
template<int WM, int WN, int ACT, bool BIAS, bool OBF>
__global__ __launch_bounds__(256) void k_mgemm(const short* __restrict__ A, const float* __restrict__ W,
        const float* __restrict__ bias, void* __restrict__ Cv,
        int M, int N, int K, long aB, long wB, long cB){
  constexpr int TM = WM * 64, TN = WN * 64;
  __shared__ short As[TM][40];   // k padded 32->40 (80B row stride)
  __shared__ short Ws[TN][40];
  int m0 = blockIdx.x * TM, n0 = blockIdx.y * TN, d = blockIdx.z;
  int t = threadIdx.x;
  int wave = t >> 6, lane = t & 63;
  int wr = wave / WN, wc = wave % WN;
  int lq = lane >> 4, lr = lane & 15;
  const short* Ad = A + (long)d * aB;
  const float* Wd = W + (long)d * wB;
  f32x4 acc[4][4];
  #pragma unroll
  for (int i = 0; i < 4; i++)
    #pragma unroll
    for (int j = 0; j < 4; j++) acc[i][j] = (f32x4){0.f, 0.f, 0.f, 0.f};

  constexpr int AREP = (TM * 32) / (256 * 8);  // s16x8 per thread
  constexpr int WREP = (TN * 32) / (256 * 4);  // float4 per thread

  for (int kb = 0; kb < K; kb += 32){
    #pragma unroll
    for (int r = 0; r < AREP; r++){
      int idx = r * 256 + t;
      int row = idx >> 2, c8 = idx & 3;
      s16x8 v = *(const s16x8*)(Ad + (long)(m0 + row) * K + kb + c8 * 8);
      *(s16x8*)&As[row][c8 * 8] = v;
    }
    #pragma unroll
    for (int r = 0; r < WREP; r++){
      int idx = r * 256 + t;
      int row = idx >> 3, c4 = idx & 7;
      int n = n0 + row;
      float4 v = {0.f, 0.f, 0.f, 0.f};
      if (n < N) v = *(const float4*)(Wd + (long)n * K + kb + c4 * 4);
      s16x4 sv = { cvtbf(v.x), cvtbf(v.y), cvtbf(v.z), cvtbf(v.w) };
      *(s16x4*)&Ws[row][c4 * 4] = sv;
    }
    __syncthreads();
    s16x8 af[4], wf[4];
    #pragma unroll
    for (int mi = 0; mi < 4; mi++) af[mi] = *(const s16x8*)&As[wr * 64 + mi * 16 + lr][lq * 8];
    #pragma unroll
    for (int ni = 0; ni < 4; ni++) wf[ni] = *(const s16x8*)&Ws[wc * 64 + ni * 16 + lr][lq * 8];
    #pragma unroll
    for (int mi = 0; mi < 4; mi++)
      #pragma unroll
      for (int ni = 0; ni < 4; ni++)
        acc[mi][ni] = __builtin_amdgcn_mfma_f32_16x16x32_bf16(af[mi], wf[ni], acc[mi][ni], 0, 0, 0);
    __syncthreads();
  }

  #pragma unroll
  for (int mi = 0; mi < 4; mi++){
    #pragma unroll
    for (int ni = 0; ni < 4; ni++){
      int n = n0 + wc * 64 + ni * 16 + lr;
      if (n < N){
        float bv = BIAS ? bias[n] : 0.f;
        #pragma unroll
        for (int r = 0; r < 4; r++){
          int m = m0 + wr * 64 + mi * 16 + lq * 4 + r;
          float v = acc[mi][ni][r] + bv;
          if (ACT == 1) v = geluf(v);
          if (OBF) ((short*)Cv)[(long)d * cB + (long)m * N + n] = cvtbf(v);
          else     ((float*)Cv)[(long)d * cB + (long)m * N + n] = v;
        }
      }
    }
  }
}

// causal depthwise conv (K=4) + silu; writes ch-major fp32 xct[db,i,l] AND row-major bf16 xcbf[db,l,i]
__global__ __launch_bounds__(256) void k_conv(const float* __restrict__ xz, const float* __restrict__ cw,
                      const float* __restrict__ cb, float* __restrict__ xct, short* __restrict__ xcbf){
  int it = blockIdx.x * 64, lc = blockIdx.y * 128, db = blockIdx.z;
  int d = db >> 3;
  int t = threadIdx.x;
  __shared__ float xs[64][131];
  const float* src = xz + (long)db * LL * 1024;
  for (int e = t; e < 131 * 64; e += 256){
    int il = e & 63, lh = e >> 6;
    int gl = lc - 3 + lh;
    xs[il][lh] = (gl >= 0) ? src[(long)gl * 1024 + it + il] : 0.f;
  }
  __syncthreads();
  const float* cwp = cw + ((long)d * DIN + it) * 4;
  const float* cbp = cb + (long)d * DIN + it;
  for (int e = t; e < 64 * 128; e += 256){
    int ll = e & 127, il = e >> 7;
    float acc = cbp[il];
    #pragma unroll
    for (int k = 0; k < 4; k++) acc += xs[il][ll + k] * cwp[il * 4 + k];
    xct[((long)db * DIN + it + il) * LL + lc + ll] = siluf(acc);
  }
  for (int e = t; e < 64 * 128; e += 256){
    int il = e & 63, lh = e >> 6;
    float acc = cbp[il];
    #pragma unroll
    for (int k = 0; k < 4; k++) acc += xs[il][lh + k] * cwp[il * 4 + k];
    xcbf[((long)db * LL + lc + lh) * DIN + it + il] = cvtbf(siluf(acc));
  }
}

// silu(z) transposed to channel-major zst[db,i,l]
__global__ __launch_bounds__(256) void k_zsilu(const float* __restrict__ xz, float* __restrict__ zst){
  int it = blockIdx.x * 64, lc = blockIdx.y * 128, db = blockIdx.z;
  int t = threadIdx.x;
  __shared__ float xs[64][129];
  const float* src = xz + (long)db * LL * 1024 + DIN;
  for (int e = t; e < 128 * 64; e += 256){
    int il = e & 63, lh = e >> 6;
    xs[il][lh] = src[(long)(lc + lh) * 1024 + it + il];
  }
  __syncthreads();
  for (int e = t; e < 64 * 128; e += 256){
    int ll = e & 127, il = e >> 7;
    zst[((long)db * DIN + it + il) * LL + lc + ll] = siluf(xs[il][ll]);
  }
}

// dt[db,i,l] = softplus(x_dbl[db,l,0:16] . dt_w[i,:] + dt_b[i]), channel-major out
__global__ __launch_bounds__(256) void k_dt(const float* __restrict__ x_dbl, const float* __restrict__ dt_w,
                     const float* __restrict__ dt_b, float* __restrict__ dtt){
  int it = blockIdx.x * 64, db = blockIdx.y;
  int d = db >> 3;
  int t = threadIdx.x;
  __shared__ float xs[256][17];
  __shared__ float wt[64][16];
  const float* xd = x_dbl + (long)db * LL * 48;
  for (int e = t; e < 256 * 16; e += 256){ int l = e >> 4, s = e & 15; xs[l][s] = xd[l * 48 + s]; }
  const float* wp = dt_w + ((long)d * DIN + it) * 16;
  for (int e = t; e < 64 * 16; e += 256){ wt[e >> 4][e & 15] = wp[e]; }
  __syncthreads();
  const float* bp = dt_b + (long)d * DIN + it;
  for (int r = 0; r < 64; r++){
    float acc = bp[r];
    #pragma unroll
    for (int s = 0; s < 16; s++) acc += xs[t][s] * wt[r][s];
    dtt[((long)db * DIN + it + r) * LL + t] = softplusf(acc);
  }
}

// windowed scan (K=8)
__global__ __launch_bounds__(256) void k_scan(const float* __restrict__ dtt, const float* __restrict__ xct,
        const float* __restrict__ zst, const float* __restrict__ x_dbl,
        const float* __restrict__ A_log, const float* __restrict__ Dp, float* __restrict__ yt){
  int i = blockIdx.x, b = blockIdx.y, d = blockIdx.z;
  int l = threadIdx.x;
  int db = d * BB + b;
  long base = ((long)db * DIN + i) * LL + l;
  __shared__ float E[256][17];
  __shared__ float Bps[256][17];
  __shared__ float dts[256];
  __shared__ float xcs[256];
  float dto = dtt[base];
  float xco = xct[base];
  dts[l] = dto; xcs[l] = xco;
  const float* alp = A_log + ((long)d * DIN + i) * NS;
  const float* xd = x_dbl + ((long)db * LL + l) * 48;
  float Cp[16];
  #pragma unroll
  for (int s = 0; s < 16; s++){
    float Av = -expf(alp[s]);
    E[l][s] = expf(Av * dto);
    Bps[l][s] = xd[16 + s];
    Cp[s] = xd[32 + s];
  }
  __syncthreads();
  float dec[16];
  #pragma unroll
  for (int s = 0; s < 16; s++) dec[s] = 1.f;
  float c0 = 0.f;
  #pragma unroll
  for (int s = 0; s < 16; s++) c0 += Bps[l][s] * Cp[s];
  float acc = dto * xco * c0;
  for (int k = 1; k < 8; k++){
    int j = l - k;
    if (j < 0) break;
    float c = 0.f;
    #pragma unroll
    for (int s = 0; s < 16; s++){ dec[s] *= E[j + 1][s]; c += dec[s] * Bps[j][s] * Cp[s]; }
    acc += dts[j] * xcs[j] * c;
  }
  float y = (acc + Dp[(long)d * DIN + i] * xco) * zst[base];
  yt[base] = y;
}

// ch-major fp32 [db,i,l] -> row-major bf16 [db,l,i]
__global__ __launch_bounds__(256) void k_y2bf(const float* __restrict__ yt, short* __restrict__ ybf){
  __shared__ float tile[64][65];
  int i0 = blockIdx.x * 64, l0 = blockIdx.y * 64, db = blockIdx.z;
  int t = threadIdx.x;
  const float* src = yt + ((long)db * DIN + i0) * LL + l0;
  for (int e = t; e < 4096; e += 256){ int ii = e >> 6, ll = e & 63; tile[ii][ll] = src[(long)ii * LL + ll]; }
  __syncthreads();
  short* dst = ybf + ((long)db * LL + l0) * DIN + i0;
  for (int e = t; e < 4096; e += 256){ int ii = e & 63, ll = e >> 6; dst[(long)ll * DIN + ii] = cvtbf(tile[ii][ll]); }
}

// LN over C of (out_pre + residual), write unflipped bf16 into comb_bf[b, t, d*256+c]
__global__ __launch_bounds__(256) void k_ln1(const float* __restrict__ out_pre, const float* __restrict__ seq,
        const float* __restrict__ ng, const float* __restrict__ nb, short* __restrict__ comb_bf){
  int l = blockIdx.x, b = blockIdx.y, d = blockIdx.z, c = threadIdx.x;
  long row = ((long)(d * BB + b) * LL + l) * DD;
  float v = out_pre[row + c] + seq[row + c];
  float s = v, q = v * v;
  #pragma unroll
  for (int off = 32; off; off >>= 1){ s += __shfl_down(s, off); q += __shfl_down(q, off); }
  __shared__ float ps[4], pq[4], mv[2];
  int wid = c >> 6;
  if ((c & 63) == 0){ ps[wid] = s; pq[wid] = q; }
  __syncthreads();
  if (c == 0){
    float ts = ps[0] + ps[1] + ps[2] + ps[3];
    float tq = pq[0] + pq[1] + pq[2] + pq[3];
    float m = ts / 256.f;
    mv[0] = m; mv[1] = rsqrtf(tq / 256.f - m * m + 1e-5f);
  }
  __syncthreads();
  float o = (v - mv[0]) * mv[1] * ng[d * DD + c] + nb[d * DD + c];
  comb_bf[((long)b * LL + perml(l, d)) * 1024 + d * DD + c] = cvtbf(o);
}

// LN over C + gate multiply
__global__ __launch_bounds__(256) void k_ln2(const float* __restrict__ h2, const float* __restrict__ lg,
        const float* __restrict__ lb, const float* __restrict__ gate, float* __restrict__ dst){
  int l = blockIdx.x, b = blockIdx.y, c = threadIdx.x;
  long row = ((long)b * LL + l) * DD;
  float v = h2[row + c];
  float s = v, q = v * v;
  #pragma unroll
  for (int off = 32; off; off >>= 1){ s += __shfl_down(s, off); q += __shfl_down(q, off); }
  __shared__ float ps[4], pq[4], mv[2];
  int wid = c >> 6;
  if ((c & 63) == 0){ ps[wid] = s; pq[wid] = q; }
  __syncthreads();
  if (c == 0){
    float ts = ps[0] + ps[1] + ps[2] + ps[3];
    float tq = pq[0] + pq[1] + pq[2] + pq[3];
    float m = ts / 256.f;
    mv[0] = m; mv[1] = rsqrtf(tq / 256.f - m * m + 1e-5f);
  }
  __syncthreads();
  float o = (v - mv[0]) * mv[1] * lg[c] + lb[c];
  dst[row + c] = o * gate[b * DD + c];
}

extern "C" void kernel_launch(void* const* d_in, const int* in_sizes, int n_in,
                              void* d_out, int out_size, void* d_ws, size_t ws_size,
                              hipStream_t stream){
  const float* feat     = (const float*)d_in[0];
  const int*   alt_idx  = (const int*)d_in[1];
  const float* in_w     = (const float*)d_in[2];
  const float* dt_w     = (const float*)d_in[3];
  const float* dt_b     = (const float*)d_in[4];
  const float* A_log    = (const float*)d_in[5];
  const float* Dp       = (const float*)d_in[6];
  const float* xp_w     = (const float*)d_in[7];
  const float* conv_w   = (const float*)d_in[8];
  const float* conv_b   = (const float*)d_in[9];
  const float* out_w    = (const float*)d_in[10];
  const float* ng       = (const float*)d_in[11];
  const float* nb       = (const float*)d_in[12];
  const float* fw1      = (const float*)d_in[13];
  const float* fb1      = (const float*)d_in[14];
  const float* fw2      = (const float*)d_in[15];
  const float* fb2      = (const float*)d_in[16];
  const float* flg      = (const float*)d_in[17];
  const float* flb      = (const float*)d_in[18];
  const float* alt_embed= (const float*)d_in[19];
  const float* gate_w   = (const float*)d_in[20];
  const float* gate_b   = (const float*)d_in[21];
  float* out = (float*)d_out;

  float* p = (float*)d_ws;
  float* x_buf = p; p += (long)BL * DD;
  float* seq   = p; p += 4L * BL * DD;
  float* xz    = p; p += 4L * BL * 1024;
  float* xct   = p; p += 4L * BB * DIN * LL;
  float* zst   = p; p += 4L * BB * DIN * LL;
  float* xdbl  = p; p += 4L * BL * 48;
  float* dtt   = p; p += 4L * BB * DIN * LL;
  float* ytb   = p; p += 4L * BB * DIN * LL;
  float* opre  = p; p += 4L * BL * DD;
  float* h2    = p; p += (long)BL * DD;
  float* gateb = p; p += 2L * BB * DD;
  short* sp = (short*)p;
  short* seq_bf  = sp; sp += 4L * BL * DD;
  short* xcbf    = sp; sp += 4L * BB * LL * DIN;
  short* ybf     = sp; sp += 4L * BB * LL * DIN;
  short* comb_bf = sp; sp += (long)BL * 1024;
  short* hfu_bf  = sp; sp += (long)BL * 512;

  k_transpose<<<2048, 256, 0, stream>>>(feat, x_buf);
  k_gate<<<16, 256, 0, stream>>>(alt_embed, alt_idx, gate_w, gate_b, gateb);

  for (int li = 0; li < NL; li++){
    k_seq<<<8192, 256, 0, stream>>>(x_buf, seq, seq_bf);
    // xz = seq @ in_w^T  (M=2048, N=1024, K=256, batch 4 dirs)
    k_mgemm<2, 2, 0, false, false><<<dim3(16, 8, 4), 256, 0, stream>>>(
        seq_bf, in_w + (long)li * NDIR * 1024 * 256, nullptr, xz,
        BL, 1024, 256, (long)BL * 256, 1024L * 256, (long)BL * 1024);
    k_conv<<<dim3(8, 2, 32), 256, 0, stream>>>(xz, conv_w + (long)li * NDIR * DIN * 4,
                                               conv_b + (long)li * NDIR * DIN, xct, xcbf);
    k_zsilu<<<dim3(8, 2, 32), 256, 0, stream>>>(xz, zst);
    // x_dbl = x_conv @ xp_w^T  (M=2048, N=48, K=512, batch 4)
    k_mgemm<4, 1, 0, false, false><<<dim3(8, 1, 4), 256, 0, stream>>>(
        xcbf, xp_w + (long)li * NDIR * 48 * 512, nullptr, xdbl,
        BL, 48, 512, (long)BB * LL * DIN, 48L * 512, (long)BL * 48);
    k_dt<<<dim3(8, 32), 256, 0, stream>>>(xdbl, dt_w + (long)li * NDIR * DIN * 16,
                                          dt_b + (long)li * NDIR * DIN, dtt);
    k_scan<<<dim3(512, 8, 4), 256, 0, stream>>>(dtt, xct, zst, xdbl,
        A_log + (long)li * NDIR * DIN * NS, Dp + (long)li * NDIR * DIN, ytb);
    k_y2bf<<<dim3(8, 4, 32), 256, 0, stream>>>(ytb, ybf);
    // out_pre = y @ out_w^T  (M=2048, N=256, K=512, batch 4)
    k_mgemm<2, 2, 0, false, false><<<dim3(16, 2, 4), 256, 0, stream>>>(
        ybf, out_w + (long)li * NDIR * 256 * 512, nullptr, opre,
        BL, 256, 512, (long)BB * LL * DIN, 256L * 512, (long)BL * 256);
    k_ln1<<<dim3(256, 8, 4), 256, 0, stream>>>(opre, seq, ng + (long)li * NDIR * DD,
                                               nb + (long)li * NDIR * DD, comb_bf);
    // hfu = gelu(comb @ fw1^T + fb1)  (M=2048, N=512, K=1024) -> bf16
    k_mgemm<2, 2, 1, true, true><<<dim3(16, 4, 1), 256, 0, stream>>>(
        comb_bf, fw1 + (long)li * 512 * 1024, fb1 + (long)li * 512, hfu_bf,
        BL, 512, 1024, 0, 0, 0);
    // h2 = hfu @ fw2^T + fb2  (M=2048, N=256, K=512)
    k_mgemm<2, 2, 0, true, false><<<dim3(16, 2, 1), 256, 0, stream>>>(
        hfu_bf, fw2 + (long)li * 256 * 512, fb2 + (long)li * 256, h2,
        BL, 256, 512, 0, 0, 0);
    float* dst = (li == NL - 1) ? out : x_buf;
    k_ln2<<<dim3(256, 8), 256, 0, stream>>>(h2, flg + (long)li * DD, flb + (long)li * DD,
                                            gateb + (long)li * BB * DD, dst);
  }
}